// Round 3
// baseline (134.139 us; speedup 1.0000x reference)
//
#include <hip/hip_runtime.h>
#include <hip/hip_bf16.h>
#include <cstddef>

#define HW 2304
#define CD 256

typedef __bf16 bf16;
typedef bf16 bf16x8 __attribute__((ext_vector_type(8)));
typedef float f32x4 __attribute__((ext_vector_type(4)));

__device__ __forceinline__ unsigned short f2bf(float f) {
    unsigned u = __float_as_uint(f);
    u += 0x7fffu + ((u >> 16) & 1u);
    return (unsigned short)(u >> 16);
}
__device__ __forceinline__ unsigned fkey(float f) {
    unsigned u = __float_as_uint(f);
    return (u & 0x80000000u) ? ~u : (u | 0x80000000u);
}
__device__ __forceinline__ float fdec(unsigned k) {
    unsigned u = (k & 0x80000000u) ? (k ^ 0x80000000u) : ~k;
    return __uint_as_float(u);
}

// ---- pass 1a: convert fine memories to bf16, K-tiled layout [z][kt][n][32] ----
// grid (576, 16): bx -> (kt = bx%8, n0 = (bx/8)*32), by = z = b*4+t
__global__ void convert_mems(const float* __restrict__ g0, const float* __restrict__ g1,
                             const float* __restrict__ l0, const float* __restrict__ l1,
                             unsigned short* __restrict__ outB) {
    const int z = blockIdx.y;
    const int b = z >> 2, t = z & 3;
    const float* src = t == 0 ? g0 : t == 1 ? g1 : t == 2 ? l0 : l1;
    const int kt = blockIdx.x & 7;
    const int n0 = (blockIdx.x >> 3) * 32;
    const int tid = threadIdx.x;
    const int n = n0 + (tid >> 3);
    const int kk = (tid & 7) * 4;
    float4 v = *(const float4*)(src + (size_t)b * (HW * CD) + (size_t)n * CD + kt * 32 + kk);
    ushort4 o;
    o.x = f2bf(v.x); o.y = f2bf(v.y); o.z = f2bf(v.z); o.w = f2bf(v.w);
    *(ushort4*)(outB + (size_t)z * (HW * CD) + (size_t)kt * (HW * 32) + (size_t)n * 32 + kk) = o;
}

// ---- pass 1b: transpose k (B,C,HW) f32 -> kT K-tiled [b][kt][m][32] bf16 ----
__global__ void transpose_k(const float* __restrict__ k, unsigned short* __restrict__ kT) {
    __shared__ float tile[32][33];
    const int bz = blockIdx.z;
    const int m0 = blockIdx.x * 32;
    const int c0 = blockIdx.y * 32;   // kt = c0/32
    const int tx = threadIdx.x, ty = threadIdx.y;   // block (32,8)
    const float* kb = k + (size_t)bz * CD * HW;
    #pragma unroll
    for (int s = 0; s < 32; s += 8)
        tile[ty + s][tx] = kb[(size_t)(c0 + ty + s) * HW + m0 + tx];
    __syncthreads();
    unsigned short* kTb = kT + (size_t)bz * (HW * CD) + (size_t)(c0 >> 5) * (HW * 32);
    #pragma unroll
    for (int s = 0; s < 32; s += 8)
        kTb[(size_t)(m0 + ty + s) * 32 + tx] = f2bf(tile[tx][ty + s]);
}

// ---- pass 2: barrier-free direct-load dual-t MFMA GEMM + sds scale + column max ----
// grid (18, 18, 8) flattened; XCD swizzle groups all blocks of one z per XCD.
__global__ __launch_bounds__(256, 2)
void fine_gemm(const unsigned short* __restrict__ memsB,  // [z][kt][2304][32]
               const unsigned short* __restrict__ kT,     // [b][kt][2304][32]
               const float* __restrict__ sds,
               unsigned* __restrict__ scratch) {
    const int h = blockIdx.x + 18 * blockIdx.y + 324 * blockIdx.z;
    const int l = (h & 7) * 324 + (h >> 3);   // 2592 % 8 == 0 -> bijective
    const int z = l / 324;                    // == h & 7
    const int rr = l - z * 324;
    const int mi = rr % 18, ni = rr / 18;
    const int b = z >> 1, p = z & 1, t0 = p * 2;
    const int n0 = ni * 128, m0 = mi * 128;

    const int tid = threadIdx.x;
    const int lane = tid & 63;
    const int w = tid >> 6;
    const int wrow = w >> 1, wcol = w & 1;
    const int lr = lane & 15;
    const int lkk = (lane >> 4) * 8;

    const unsigned short* A0g = memsB + (size_t)(b * 4 + t0) * (HW * CD);
    const unsigned short* A1g = memsB + (size_t)(b * 4 + t0 + 1) * (HW * CD);
    const unsigned short* Bg  = kT + (size_t)b * (HW * CD);

    const size_t oa = (size_t)(n0 + wrow * 64 + lr) * 32 + lkk;
    const size_t ob = (size_t)(m0 + wcol * 64 + lr) * 32 + lkk;

    f32x4 acc0[4][4] = {};
    f32x4 acc1[4][4] = {};

    #pragma unroll
    for (int kt = 0; kt < 8; ++kt) {
        const size_t ko = (size_t)kt * (HW * 32);
        bf16x8 a0f[4], a1f[4], bfr[4];
        #pragma unroll
        for (int i = 0; i < 4; ++i) {
            a0f[i] = *(const bf16x8*)(A0g + ko + oa + (size_t)i * (16 * 32));
            a1f[i] = *(const bf16x8*)(A1g + ko + oa + (size_t)i * (16 * 32));
            bfr[i] = *(const bf16x8*)(Bg  + ko + ob + (size_t)i * (16 * 32));
        }
        #pragma unroll
        for (int i = 0; i < 4; ++i) {
            #pragma unroll
            for (int j = 0; j < 4; ++j) {
                acc0[i][j] = __builtin_amdgcn_mfma_f32_16x16x32_bf16(a0f[i], bfr[j], acc0[i][j], 0, 0, 0);
                acc1[i][j] = __builtin_amdgcn_mfma_f32_16x16x32_bf16(a1f[i], bfr[j], acc1[i][j], 0, 0, 0);
            }
        }
    }

    // epilogue: sds scale for the local pair (p == 1), one read serves both t's
    if (p == 1) {
        const float* sb = sds + (size_t)b * HW * HW;
        #pragma unroll
        for (int i = 0; i < 4; ++i) {
            #pragma unroll
            for (int j = 0; j < 4; ++j) {
                #pragma unroll
                for (int r = 0; r < 4; ++r) {
                    const int n = n0 + wrow * 64 + i * 16 + (lane >> 4) * 4 + r;
                    const int m = m0 + wcol * 64 + j * 16 + (lane & 15);
                    const float sv = sb[(size_t)n * HW + m];
                    acc0[i][j][r] *= sv;
                    acc1[i][j][r] *= sv;
                }
            }
        }
    }

    // column max over the n (row) dimension per t, then device atomicMax
    #pragma unroll
    for (int j = 0; j < 4; ++j) {
        float v0 = acc0[0][j][0];
        float v1 = acc1[0][j][0];
        #pragma unroll
        for (int i = 0; i < 4; ++i) {
            #pragma unroll
            for (int r = 0; r < 4; ++r) {
                v0 = fmaxf(v0, acc0[i][j][r]);
                v1 = fmaxf(v1, acc1[i][j][r]);
            }
        }
        v0 = fmaxf(v0, __shfl_xor(v0, 16));
        v0 = fmaxf(v0, __shfl_xor(v0, 32));
        v1 = fmaxf(v1, __shfl_xor(v1, 16));
        v1 = fmaxf(v1, __shfl_xor(v1, 32));
        if (lane < 16) {
            const int m = m0 + wcol * 64 + j * 16 + lane;
            atomicMax(&scratch[(size_t)(b * 4 + t0) * HW + m], fkey(v0));
            atomicMax(&scratch[(size_t)(b * 4 + t0 + 1) * HW + m], fkey(v1));
        }
    }
}

// ---- pass 3: decode fine maxes + exact f32 coarse dots ----
__global__ void finalize(const unsigned* __restrict__ scratch,
                         const float* __restrict__ kf,
                         const float* __restrict__ c0, const float* __restrict__ c1,
                         const float* __restrict__ c2, const float* __restrict__ c3,
                         const float* __restrict__ c4, const float* __restrict__ c5,
                         float* __restrict__ out) {
    const int b = blockIdx.y;
    const int m = blockIdx.x * 256 + threadIdx.x;
    #pragma unroll
    for (int t = 0; t < 4; ++t)
        out[((size_t)b * 10 + t) * HW + m] = fdec(scratch[(size_t)(b * 4 + t) * HW + m]);
    float a0 = 0, a1 = 0, a2 = 0, a3 = 0, a4 = 0, a5 = 0;
    const float* kb = kf + (size_t)b * CD * HW;
    for (int c = 0; c < CD; ++c) {
        const float kv = kb[(size_t)c * HW + m];
        a0 = fmaf(c0[b * CD + c], kv, a0);
        a1 = fmaf(c1[b * CD + c], kv, a1);
        a2 = fmaf(c2[b * CD + c], kv, a2);
        a3 = fmaf(c3[b * CD + c], kv, a3);
        a4 = fmaf(c4[b * CD + c], kv, a4);
        a5 = fmaf(c5[b * CD + c], kv, a5);
    }
    out[((size_t)b * 10 + 4) * HW + m] = a0;
    out[((size_t)b * 10 + 5) * HW + m] = a1;
    out[((size_t)b * 10 + 6) * HW + m] = a2;
    out[((size_t)b * 10 + 7) * HW + m] = a3;
    out[((size_t)b * 10 + 8) * HW + m] = a4;
    out[((size_t)b * 10 + 9) * HW + m] = a5;
}

extern "C" void kernel_launch(void* const* d_in, const int* in_sizes, int n_in,
                              void* d_out, int out_size, void* d_ws, size_t ws_size,
                              hipStream_t stream) {
    const float* norm_key = (const float*)d_in[0];
    const float* gbg = (const float*)d_in[1];
    const float* gfg = (const float*)d_in[2];
    const float* lbg = (const float*)d_in[3];
    const float* lfg = (const float*)d_in[4];
    const float* obg = (const float*)d_in[5];
    const float* ofg = (const float*)d_in[6];
    const float* sbg = (const float*)d_in[7];
    const float* sfg = (const float*)d_in[8];
    const float* lgbg = (const float*)d_in[9];
    const float* lgfg = (const float*)d_in[10];
    const float* sds = (const float*)d_in[11];
    float* out = (float*)d_out;

    // ws layout: [scratch keys 16*2304 u32][memsB bf16 16*2304*256][kT bf16 4*2304*256]
    unsigned* scratch = (unsigned*)d_ws;
    const size_t scratch_bytes = (size_t)16 * HW * sizeof(unsigned);
    unsigned short* memsB = (unsigned short*)((char*)d_ws + scratch_bytes);
    const size_t mems_bytes = (size_t)16 * HW * CD * sizeof(unsigned short);
    unsigned short* kT = (unsigned short*)((char*)d_ws + scratch_bytes + mems_bytes);

    hipMemsetAsync(d_ws, 0, scratch_bytes, stream);
    convert_mems<<<dim3(576, 16), 256, 0, stream>>>(gbg, gfg, lbg, lfg, memsB);
    transpose_k<<<dim3(72, 8, 4), dim3(32, 8), 0, stream>>>(norm_key, kT);
    fine_gemm<<<dim3(18, 18, 8), 256, 0, stream>>>(memsB, kT, sds, scratch);
    finalize<<<dim3(9, 4), 256, 0, stream>>>(scratch, norm_key, obg, ofg, sbg, sfg, lgbg, lgfg, out);
}

// Round 4
// 105.763 us; speedup vs baseline: 1.2683x; 1.2683x over previous
//
#include <hip/hip_runtime.h>
#include <hip/hip_bf16.h>
#include <cstddef>

#define HW 2304
#define CD 256

typedef __bf16 bf16;
typedef bf16 bf16x8 __attribute__((ext_vector_type(8)));
typedef float f32x4 __attribute__((ext_vector_type(4)));

__device__ __forceinline__ unsigned short f2bf(float f) {
    unsigned u = __float_as_uint(f);
    u += 0x7fffu + ((u >> 16) & 1u);
    return (unsigned short)(u >> 16);
}
__device__ __forceinline__ unsigned fkey(float f) {
    unsigned u = __float_as_uint(f);
    return (u & 0x80000000u) ? ~u : (u | 0x80000000u);
}
__device__ __forceinline__ float fdec(unsigned k) {
    unsigned u = (k & 0x80000000u) ? (k ^ 0x80000000u) : ~k;
    return __uint_as_float(u);
}

// ---- pass 1a: convert fine memories to bf16, K-tiled + chunk-swizzled ----
// layout [z][kt][n][32], physical 8-elem chunk p = c ^ ((n>>1)&3)
__global__ void convert_mems(const float* __restrict__ g0, const float* __restrict__ g1,
                             const float* __restrict__ l0, const float* __restrict__ l1,
                             unsigned short* __restrict__ outB) {
    const int z = blockIdx.y;
    const int b = z >> 2, t = z & 3;
    const float* src = t == 0 ? g0 : t == 1 ? g1 : t == 2 ? l0 : l1;
    const int kt = blockIdx.x & 7;
    const int n0 = (blockIdx.x >> 3) * 32;
    const int tid = threadIdx.x;
    const int n = n0 + (tid >> 3);
    const int kk = (tid & 7) * 4;                 // logical elem offset in row
    float4 v = *(const float4*)(src + (size_t)b * (HW * CD) + (size_t)n * CD + kt * 32 + kk);
    ushort4 o;
    o.x = f2bf(v.x); o.y = f2bf(v.y); o.z = f2bf(v.z); o.w = f2bf(v.w);
    const int p = (kk >> 3) ^ ((n >> 1) & 3);     // physical chunk
    *(ushort4*)(outB + (size_t)z * (HW * CD) + (size_t)kt * (HW * 32)
                + (size_t)n * 32 + p * 8 + (kk & 7)) = o;
}

// ---- pass 1b: transpose k -> kT K-tiled [b][kt][m][32] bf16, chunk-swizzled ----
__global__ void transpose_k(const float* __restrict__ k, unsigned short* __restrict__ kT) {
    __shared__ float tile[32][33];
    const int bz = blockIdx.z;
    const int m0 = blockIdx.x * 32;
    const int c0 = blockIdx.y * 32;   // kt = c0/32
    const int tx = threadIdx.x, ty = threadIdx.y;   // block (32,8)
    const float* kb = k + (size_t)bz * CD * HW;
    #pragma unroll
    for (int s = 0; s < 32; s += 8)
        tile[ty + s][tx] = kb[(size_t)(c0 + ty + s) * HW + m0 + tx];
    __syncthreads();
    unsigned short* kTb = kT + (size_t)bz * (HW * CD) + (size_t)(c0 >> 5) * (HW * 32);
    #pragma unroll
    for (int s = 0; s < 32; s += 8) {
        const int m = m0 + ty + s;
        const int p = (tx >> 3) ^ ((m >> 1) & 3);
        kTb[(size_t)m * 32 + p * 8 + (tx & 7)] = f2bf(tile[tx][ty + s]);
    }
}

// ---- pass 2: dual-t MFMA GEMM, counted-vmcnt depth-2 pipeline + swizzled LDS ----
// grid (18, 18, 8) flattened; XCD swizzle groups all blocks of one z per XCD.
__global__ __launch_bounds__(256, 2)
void fine_gemm(const unsigned short* __restrict__ memsB,  // [z][kt][2304][32] swz
               const unsigned short* __restrict__ kT,     // [b][kt][2304][32] swz
               const float* __restrict__ sds,
               unsigned* __restrict__ scratch) {
    __shared__ unsigned short A0l[2][128][32];   // 16KB
    __shared__ unsigned short A1l[2][128][32];   // 16KB
    __shared__ unsigned short Bl[2][128][32];    // 16KB

    const int h = blockIdx.x + 18 * blockIdx.y + 324 * blockIdx.z;
    const int l = (h & 7) * 324 + (h >> 3);   // 2592 % 8 == 0 -> bijective
    const int z = l / 324;
    const int rr = l - z * 324;
    const int mi = rr % 18, ni = rr / 18;
    const int b = z >> 1, p = z & 1, t0 = p * 2;
    const int n0 = ni * 128, m0 = mi * 128;

    const int tid = threadIdx.x;
    const int lane = tid & 63;
    const int w = tid >> 6;
    const int wrow = w >> 1, wcol = w & 1;

    const unsigned short* A0g = memsB + (size_t)(b * 4 + t0) * (HW * CD);
    const unsigned short* A1g = memsB + (size_t)(b * 4 + t0 + 1) * (HW * CD);
    const unsigned short* Bg  = kT + (size_t)b * (HW * CD);

    const int srow = lane >> 2;          // staging: row within 16-row stripe
    const int scol = (lane & 3) * 8;     // staging: physical 16B chunk

    const int lr = lane & 15;
    const int pofs = ((lane >> 4) ^ ((lr >> 1) & 3)) * 8;   // swizzled read chunk

    f32x4 acc0[4][4] = {};
    f32x4 acc1[4][4] = {};

#define STAGE(buf, kt_)                                                                    \
    do {                                                                                   \
        const size_t ko = (size_t)(kt_) * (HW * 32);                                       \
        _Pragma("unroll")                                                                  \
        for (int s = 0; s < 2; ++s) {                                                      \
            const int r = w * 32 + s * 16;                                                 \
            const size_t goa = ko + (size_t)(n0 + r + srow) * 32 + scol;                   \
            const size_t gob = ko + (size_t)(m0 + r + srow) * 32 + scol;                   \
            __builtin_amdgcn_global_load_lds(                                              \
                (const __attribute__((address_space(1))) unsigned int*)(A0g + goa),        \
                (__attribute__((address_space(3))) unsigned int*)&A0l[buf][r][0], 16, 0, 0); \
            __builtin_amdgcn_global_load_lds(                                              \
                (const __attribute__((address_space(1))) unsigned int*)(A1g + goa),        \
                (__attribute__((address_space(3))) unsigned int*)&A1l[buf][r][0], 16, 0, 0); \
            __builtin_amdgcn_global_load_lds(                                              \
                (const __attribute__((address_space(1))) unsigned int*)(Bg + gob),         \
                (__attribute__((address_space(3))) unsigned int*)&Bl[buf][r][0], 16, 0, 0); \
        }                                                                                  \
    } while (0)

    STAGE(0, 0);
    STAGE(1, 1);

    #pragma unroll
    for (int kt = 0; kt < 8; ++kt) {
        const int cur = kt & 1;
        // wait for this K-step's stage (6 loads) to land; keep next 6 in flight
        if (kt < 7) {
            asm volatile("s_waitcnt vmcnt(6)" ::: "memory");
        } else {
            asm volatile("s_waitcnt vmcnt(0)" ::: "memory");
        }
        __builtin_amdgcn_s_barrier();

        bf16x8 a0f[4], a1f[4], bfr[4];
        #pragma unroll
        for (int i = 0; i < 4; ++i) {
            a0f[i] = *(const bf16x8*)&A0l[cur][wrow * 64 + i * 16 + lr][pofs];
            a1f[i] = *(const bf16x8*)&A1l[cur][wrow * 64 + i * 16 + lr][pofs];
            bfr[i] = *(const bf16x8*)&Bl[cur][wcol * 64 + i * 16 + lr][pofs];
        }
        // all my reads complete before anyone overwrites this buffer
        asm volatile("s_waitcnt lgkmcnt(0)" ::: "memory");
        __builtin_amdgcn_s_barrier();
        if (kt < 6) STAGE(cur, kt + 2);

        __builtin_amdgcn_s_setprio(1);
        #pragma unroll
        for (int i = 0; i < 4; ++i) {
            #pragma unroll
            for (int j = 0; j < 4; ++j) {
                acc0[i][j] = __builtin_amdgcn_mfma_f32_16x16x32_bf16(a0f[i], bfr[j], acc0[i][j], 0, 0, 0);
                acc1[i][j] = __builtin_amdgcn_mfma_f32_16x16x32_bf16(a1f[i], bfr[j], acc1[i][j], 0, 0, 0);
            }
        }
        __builtin_amdgcn_s_setprio(0);
    }
#undef STAGE

    // epilogue: sds scale for the local pair (p == 1), one read serves both t's
    if (p == 1) {
        const float* sb = sds + (size_t)b * HW * HW;
        #pragma unroll
        for (int i = 0; i < 4; ++i) {
            #pragma unroll
            for (int j = 0; j < 4; ++j) {
                #pragma unroll
                for (int r = 0; r < 4; ++r) {
                    const int n = n0 + wrow * 64 + i * 16 + (lane >> 4) * 4 + r;
                    const int m = m0 + wcol * 64 + j * 16 + (lane & 15);
                    const float sv = sb[(size_t)n * HW + m];
                    acc0[i][j][r] *= sv;
                    acc1[i][j][r] *= sv;
                }
            }
        }
    }

    // column max over the n (row) dimension per t, then device atomicMax
    #pragma unroll
    for (int j = 0; j < 4; ++j) {
        float v0 = acc0[0][j][0];
        float v1 = acc1[0][j][0];
        #pragma unroll
        for (int i = 0; i < 4; ++i) {
            #pragma unroll
            for (int r = 0; r < 4; ++r) {
                v0 = fmaxf(v0, acc0[i][j][r]);
                v1 = fmaxf(v1, acc1[i][j][r]);
            }
        }
        v0 = fmaxf(v0, __shfl_xor(v0, 16));
        v0 = fmaxf(v0, __shfl_xor(v0, 32));
        v1 = fmaxf(v1, __shfl_xor(v1, 16));
        v1 = fmaxf(v1, __shfl_xor(v1, 32));
        if (lane < 16) {
            const int m = m0 + wcol * 64 + j * 16 + lane;
            atomicMax(&scratch[(size_t)(b * 4 + t0) * HW + m], fkey(v0));
            atomicMax(&scratch[(size_t)(b * 4 + t0 + 1) * HW + m], fkey(v1));
        }
    }
}

// ---- pass 3: decode fine maxes + exact f32 coarse dots ----
__global__ void finalize(const unsigned* __restrict__ scratch,
                         const float* __restrict__ kf,
                         const float* __restrict__ c0, const float* __restrict__ c1,
                         const float* __restrict__ c2, const float* __restrict__ c3,
                         const float* __restrict__ c4, const float* __restrict__ c5,
                         float* __restrict__ out) {
    const int b = blockIdx.y;
    const int m = blockIdx.x * 256 + threadIdx.x;
    #pragma unroll
    for (int t = 0; t < 4; ++t)
        out[((size_t)b * 10 + t) * HW + m] = fdec(scratch[(size_t)(b * 4 + t) * HW + m]);
    float a0 = 0, a1 = 0, a2 = 0, a3 = 0, a4 = 0, a5 = 0;
    const float* kb = kf + (size_t)b * CD * HW;
    for (int c = 0; c < CD; ++c) {
        const float kv = kb[(size_t)c * HW + m];
        a0 = fmaf(c0[b * CD + c], kv, a0);
        a1 = fmaf(c1[b * CD + c], kv, a1);
        a2 = fmaf(c2[b * CD + c], kv, a2);
        a3 = fmaf(c3[b * CD + c], kv, a3);
        a4 = fmaf(c4[b * CD + c], kv, a4);
        a5 = fmaf(c5[b * CD + c], kv, a5);
    }
    out[((size_t)b * 10 + 4) * HW + m] = a0;
    out[((size_t)b * 10 + 5) * HW + m] = a1;
    out[((size_t)b * 10 + 6) * HW + m] = a2;
    out[((size_t)b * 10 + 7) * HW + m] = a3;
    out[((size_t)b * 10 + 8) * HW + m] = a4;
    out[((size_t)b * 10 + 9) * HW + m] = a5;
}

extern "C" void kernel_launch(void* const* d_in, const int* in_sizes, int n_in,
                              void* d_out, int out_size, void* d_ws, size_t ws_size,
                              hipStream_t stream) {
    const float* norm_key = (const float*)d_in[0];
    const float* gbg = (const float*)d_in[1];
    const float* gfg = (const float*)d_in[2];
    const float* lbg = (const float*)d_in[3];
    const float* lfg = (const float*)d_in[4];
    const float* obg = (const float*)d_in[5];
    const float* ofg = (const float*)d_in[6];
    const float* sbg = (const float*)d_in[7];
    const float* sfg = (const float*)d_in[8];
    const float* lgbg = (const float*)d_in[9];
    const float* lgfg = (const float*)d_in[10];
    const float* sds = (const float*)d_in[11];
    float* out = (float*)d_out;

    // ws layout: [scratch keys 16*2304 u32][memsB bf16 16*2304*256][kT bf16 4*2304*256]
    unsigned* scratch = (unsigned*)d_ws;
    const size_t scratch_bytes = (size_t)16 * HW * sizeof(unsigned);
    unsigned short* memsB = (unsigned short*)((char*)d_ws + scratch_bytes);
    const size_t mems_bytes = (size_t)16 * HW * CD * sizeof(unsigned short);
    unsigned short* kT = (unsigned short*)((char*)d_ws + scratch_bytes + mems_bytes);

    hipMemsetAsync(d_ws, 0, scratch_bytes, stream);
    convert_mems<<<dim3(576, 16), 256, 0, stream>>>(gbg, gfg, lbg, lfg, memsB);
    transpose_k<<<dim3(72, 8, 4), dim3(32, 8), 0, stream>>>(norm_key, kT);
    fine_gemm<<<dim3(18, 18, 8), 256, 0, stream>>>(memsB, kT, sds, scratch);
    finalize<<<dim3(9, 4), 256, 0, stream>>>(scratch, norm_key, obg, ofg, sbg, sfg, lgbg, lgfg, out);
}

// Round 5
// 95.926 us; speedup vs baseline: 1.3984x; 1.1025x over previous
//
#include <hip/hip_runtime.h>
#include <hip/hip_bf16.h>
#include <cstddef>

#define HW 2304
#define CD 256

typedef __bf16 bf16;
typedef bf16 bf16x8 __attribute__((ext_vector_type(8)));
typedef float f32x4 __attribute__((ext_vector_type(4)));

__device__ __forceinline__ unsigned short f2bf(float f) {
    unsigned u = __float_as_uint(f);
    u += 0x7fffu + ((u >> 16) & 1u);
    return (unsigned short)(u >> 16);
}
__device__ __forceinline__ unsigned fkey(float f) {
    unsigned u = __float_as_uint(f);
    return (u & 0x80000000u) ? ~u : (u | 0x80000000u);
}
__device__ __forceinline__ float fdec(unsigned k) {
    unsigned u = (k & 0x80000000u) ? (k ^ 0x80000000u) : ~k;
    return __uint_as_float(u);
}

// ---- pass 1 (fused): scratch zero + convert mems (K-tiled swizzled bf16)
//                      + transpose k -> kT (K-tiled swizzled bf16) ----
// blocks [0,9216): convert; [9216,11520): transpose; [11520,11664): zero scratch
__global__ void prep(const float* __restrict__ g0, const float* __restrict__ g1,
                     const float* __restrict__ l0, const float* __restrict__ l1,
                     const float* __restrict__ k,
                     unsigned short* __restrict__ outB,
                     unsigned short* __restrict__ kT,
                     unsigned* __restrict__ scratch) {
    __shared__ float tile[32][33];
    const int bid = blockIdx.x;
    const int tid = threadIdx.x;
    if (bid < 9216) {
        // convert: layout [z][kt][n][32], physical chunk p = c ^ ((n>>1)&3)
        const int bx = bid % 576, z = bid / 576;
        const int b = z >> 2, t = z & 3;
        const float* src = t == 0 ? g0 : t == 1 ? g1 : t == 2 ? l0 : l1;
        const int kt = bx & 7;
        const int n0 = (bx >> 3) * 32;
        const int n = n0 + (tid >> 3);
        const int kk = (tid & 7) * 4;
        float4 v = *(const float4*)(src + (size_t)b * (HW * CD) + (size_t)n * CD + kt * 32 + kk);
        ushort4 o;
        o.x = f2bf(v.x); o.y = f2bf(v.y); o.z = f2bf(v.z); o.w = f2bf(v.w);
        const int p = (kk >> 3) ^ ((n >> 1) & 3);
        *(ushort4*)(outB + (size_t)z * (HW * CD) + (size_t)kt * (HW * 32)
                    + (size_t)n * 32 + p * 8 + (kk & 7)) = o;
    } else if (bid < 11520) {
        const int t3 = bid - 9216;              // orig grid (72,8,4)
        const int m0 = (t3 % 72) * 32;
        const int c0 = ((t3 / 72) & 7) * 32;    // kt = c0/32
        const int bz = t3 / 576;
        const int tx = tid & 31, ty = tid >> 5;
        const float* kb = k + (size_t)bz * CD * HW;
        #pragma unroll
        for (int s = 0; s < 32; s += 8)
            tile[ty + s][tx] = kb[(size_t)(c0 + ty + s) * HW + m0 + tx];
        __syncthreads();
        unsigned short* kTb = kT + (size_t)bz * (HW * CD) + (size_t)(c0 >> 5) * (HW * 32);
        #pragma unroll
        for (int s = 0; s < 32; s += 8) {
            const int m = m0 + ty + s;
            const int p = (tx >> 3) ^ ((m >> 1) & 3);
            kTb[(size_t)m * 32 + p * 8 + (tx & 7)] = f2bf(tile[tx][ty + s]);
        }
    } else {
        const int i = (bid - 11520) * 256 + tid;   // 144*256 = 36864 = 16*HW
        scratch[i] = 0u;
    }
}

// ---- pass 2: dual-t MFMA GEMM, counted-vmcnt depth-2 pipeline + swizzled LDS ----
// grid 2592 linear. Balanced pair-swizzle: XCD pair {2c,2c+1} handles z in {2c,2c+1}
// (same b); consecutive blocks on an XCD alternate z at the same (mi,ni) tile.
__global__ __launch_bounds__(256, 2)
void fine_gemm(const unsigned short* __restrict__ memsB,  // [z][kt][2304][32] swz
               const unsigned short* __restrict__ kT,     // [b][kt][2304][32] swz
               const float* __restrict__ sds,
               unsigned* __restrict__ scratch) {
    __shared__ unsigned short A0l[2][128][32];   // 16KB
    __shared__ unsigned short A1l[2][128][32];   // 16KB
    __shared__ unsigned short Bl[2][128][32];    // 16KB

    const int h = blockIdx.x;
    const int x = h & 7, j = h >> 3;             // x = XCD slot, j in [0,324)
    const int c = x >> 1;                        // batch
    const int z = c * 2 + (j & 1);               // z in {2c, 2c+1}
    const int idx = (x & 1) * 162 + (j >> 1);    // tile index in [0,324)
    const int mi = idx % 18, ni = idx / 18;
    const int b = z >> 1, p = z & 1, t0 = p * 2;
    const int n0 = ni * 128, m0 = mi * 128;

    const int tid = threadIdx.x;
    const int lane = tid & 63;
    const int w = tid >> 6;
    const int wrow = w >> 1, wcol = w & 1;

    const unsigned short* A0g = memsB + (size_t)(b * 4 + t0) * (HW * CD);
    const unsigned short* A1g = memsB + (size_t)(b * 4 + t0 + 1) * (HW * CD);
    const unsigned short* Bg  = kT + (size_t)b * (HW * CD);

    const int srow = lane >> 2;          // staging: row within 16-row stripe
    const int scol = (lane & 3) * 8;     // staging: physical 16B chunk

    const int lr = lane & 15;
    const int pofs = ((lane >> 4) ^ ((lr >> 1) & 3)) * 8;   // swizzled read chunk

    f32x4 acc0[4][4] = {};
    f32x4 acc1[4][4] = {};

#define STAGE(buf, kt_)                                                                    \
    do {                                                                                   \
        const size_t ko = (size_t)(kt_) * (HW * 32);                                       \
        _Pragma("unroll")                                                                  \
        for (int s = 0; s < 2; ++s) {                                                      \
            const int r = w * 32 + s * 16;                                                 \
            const size_t goa = ko + (size_t)(n0 + r + srow) * 32 + scol;                   \
            const size_t gob = ko + (size_t)(m0 + r + srow) * 32 + scol;                   \
            __builtin_amdgcn_global_load_lds(                                              \
                (const __attribute__((address_space(1))) unsigned int*)(A0g + goa),        \
                (__attribute__((address_space(3))) unsigned int*)&A0l[buf][r][0], 16, 0, 0); \
            __builtin_amdgcn_global_load_lds(                                              \
                (const __attribute__((address_space(1))) unsigned int*)(A1g + goa),        \
                (__attribute__((address_space(3))) unsigned int*)&A1l[buf][r][0], 16, 0, 0); \
            __builtin_amdgcn_global_load_lds(                                              \
                (const __attribute__((address_space(1))) unsigned int*)(Bg + gob),         \
                (__attribute__((address_space(3))) unsigned int*)&Bl[buf][r][0], 16, 0, 0); \
        }                                                                                  \
    } while (0)

    STAGE(0, 0);
    STAGE(1, 1);

    #pragma unroll
    for (int kt = 0; kt < 8; ++kt) {
        const int cur = kt & 1;
        if (kt < 7) {
            asm volatile("s_waitcnt vmcnt(6)" ::: "memory");
        } else {
            asm volatile("s_waitcnt vmcnt(0)" ::: "memory");
        }
        __builtin_amdgcn_s_barrier();

        bf16x8 a0f[4], a1f[4], bfr[4];
        #pragma unroll
        for (int i = 0; i < 4; ++i) {
            a0f[i] = *(const bf16x8*)&A0l[cur][wrow * 64 + i * 16 + lr][pofs];
            a1f[i] = *(const bf16x8*)&A1l[cur][wrow * 64 + i * 16 + lr][pofs];
            bfr[i] = *(const bf16x8*)&Bl[cur][wcol * 64 + i * 16 + lr][pofs];
        }
        asm volatile("s_waitcnt lgkmcnt(0)" ::: "memory");
        __builtin_amdgcn_s_barrier();
        if (kt < 6) STAGE(cur, kt + 2);

        __builtin_amdgcn_s_setprio(1);
        #pragma unroll
        for (int i = 0; i < 4; ++i) {
            #pragma unroll
            for (int j2 = 0; j2 < 4; ++j2) {
                acc0[i][j2] = __builtin_amdgcn_mfma_f32_16x16x32_bf16(a0f[i], bfr[j2], acc0[i][j2], 0, 0, 0);
                acc1[i][j2] = __builtin_amdgcn_mfma_f32_16x16x32_bf16(a1f[i], bfr[j2], acc1[i][j2], 0, 0, 0);
            }
        }
        __builtin_amdgcn_s_setprio(0);
    }
#undef STAGE

    // epilogue: sds scale for the local pair (p == 1), one read serves both t's
    if (p == 1) {
        const float* sb = sds + (size_t)b * HW * HW;
        #pragma unroll
        for (int i = 0; i < 4; ++i) {
            #pragma unroll
            for (int j2 = 0; j2 < 4; ++j2) {
                #pragma unroll
                for (int r = 0; r < 4; ++r) {
                    const int n = n0 + wrow * 64 + i * 16 + (lane >> 4) * 4 + r;
                    const int m = m0 + wcol * 64 + j2 * 16 + (lane & 15);
                    const float sv = sb[(size_t)n * HW + m];
                    acc0[i][j2][r] *= sv;
                    acc1[i][j2][r] *= sv;
                }
            }
        }
    }

    // column max over the n (row) dimension per t, then device atomicMax
    #pragma unroll
    for (int j2 = 0; j2 < 4; ++j2) {
        float v0 = acc0[0][j2][0];
        float v1 = acc1[0][j2][0];
        #pragma unroll
        for (int i = 0; i < 4; ++i) {
            #pragma unroll
            for (int r = 0; r < 4; ++r) {
                v0 = fmaxf(v0, acc0[i][j2][r]);
                v1 = fmaxf(v1, acc1[i][j2][r]);
            }
        }
        v0 = fmaxf(v0, __shfl_xor(v0, 16));
        v0 = fmaxf(v0, __shfl_xor(v0, 32));
        v1 = fmaxf(v1, __shfl_xor(v1, 16));
        v1 = fmaxf(v1, __shfl_xor(v1, 32));
        if (lane < 16) {
            const int m = m0 + wcol * 64 + j2 * 16 + lane;
            atomicMax(&scratch[(size_t)(b * 4 + t0) * HW + m], fkey(v0));
            atomicMax(&scratch[(size_t)(b * 4 + t0 + 1) * HW + m], fkey(v1));
        }
    }
}

// ---- pass 3: decode fine maxes + exact f32 coarse dots ----
__global__ void finalize(const unsigned* __restrict__ scratch,
                         const float* __restrict__ kf,
                         const float* __restrict__ c0, const float* __restrict__ c1,
                         const float* __restrict__ c2, const float* __restrict__ c3,
                         const float* __restrict__ c4, const float* __restrict__ c5,
                         float* __restrict__ out) {
    const int b = blockIdx.y;
    const int m = blockIdx.x * 256 + threadIdx.x;
    #pragma unroll
    for (int t = 0; t < 4; ++t)
        out[((size_t)b * 10 + t) * HW + m] = fdec(scratch[(size_t)(b * 4 + t) * HW + m]);
    float a0 = 0, a1 = 0, a2 = 0, a3 = 0, a4 = 0, a5 = 0;
    const float* kb = kf + (size_t)b * CD * HW;
    for (int c = 0; c < CD; ++c) {
        const float kv = kb[(size_t)c * HW + m];
        a0 = fmaf(c0[b * CD + c], kv, a0);
        a1 = fmaf(c1[b * CD + c], kv, a1);
        a2 = fmaf(c2[b * CD + c], kv, a2);
        a3 = fmaf(c3[b * CD + c], kv, a3);
        a4 = fmaf(c4[b * CD + c], kv, a4);
        a5 = fmaf(c5[b * CD + c], kv, a5);
    }
    out[((size_t)b * 10 + 4) * HW + m] = a0;
    out[((size_t)b * 10 + 5) * HW + m] = a1;
    out[((size_t)b * 10 + 6) * HW + m] = a2;
    out[((size_t)b * 10 + 7) * HW + m] = a3;
    out[((size_t)b * 10 + 8) * HW + m] = a4;
    out[((size_t)b * 10 + 9) * HW + m] = a5;
}

extern "C" void kernel_launch(void* const* d_in, const int* in_sizes, int n_in,
                              void* d_out, int out_size, void* d_ws, size_t ws_size,
                              hipStream_t stream) {
    const float* norm_key = (const float*)d_in[0];
    const float* gbg = (const float*)d_in[1];
    const float* gfg = (const float*)d_in[2];
    const float* lbg = (const float*)d_in[3];
    const float* lfg = (const float*)d_in[4];
    const float* obg = (const float*)d_in[5];
    const float* ofg = (const float*)d_in[6];
    const float* sbg = (const float*)d_in[7];
    const float* sfg = (const float*)d_in[8];
    const float* lgbg = (const float*)d_in[9];
    const float* lgfg = (const float*)d_in[10];
    const float* sds = (const float*)d_in[11];
    float* out = (float*)d_out;

    // ws layout: [scratch keys 16*2304 u32][memsB bf16 16*2304*256][kT bf16 4*2304*256]
    unsigned* scratch = (unsigned*)d_ws;
    const size_t scratch_bytes = (size_t)16 * HW * sizeof(unsigned);
    unsigned short* memsB = (unsigned short*)((char*)d_ws + scratch_bytes);
    const size_t mems_bytes = (size_t)16 * HW * CD * sizeof(unsigned short);
    unsigned short* kT = (unsigned short*)((char*)d_ws + scratch_bytes + mems_bytes);

    prep<<<11664, 256, 0, stream>>>(gbg, gfg, lbg, lfg, norm_key, memsB, kT, scratch);
    fine_gemm<<<2592, 256, 0, stream>>>(memsB, kT, sds, scratch);
    finalize<<<dim3(9, 4), 256, 0, stream>>>(scratch, norm_key, obg, ofg, sbg, sfg, lgbg, lgfg, out);
}

// Round 6
// 92.835 us; speedup vs baseline: 1.4449x; 1.0333x over previous
//
#include <hip/hip_runtime.h>
#include <hip/hip_bf16.h>
#include <cstddef>

#define HW 2304
#define CD 256

typedef __bf16 bf16;
typedef bf16 bf16x8 __attribute__((ext_vector_type(8)));
typedef float f32x4 __attribute__((ext_vector_type(4)));

__device__ __forceinline__ unsigned short f2bf(float f) {
    unsigned u = __float_as_uint(f);
    u += 0x7fffu + ((u >> 16) & 1u);
    return (unsigned short)(u >> 16);
}
__device__ __forceinline__ unsigned fkey(float f) {
    unsigned u = __float_as_uint(f);
    return (u & 0x80000000u) ? ~u : (u | 0x80000000u);
}
__device__ __forceinline__ float fdec(unsigned k) {
    unsigned u = (k & 0x80000000u) ? (k ^ 0x80000000u) : ~k;
    return __uint_as_float(u);
}

// ---- pass 1 (fused): convert mems + transpose k + zero scratch + coarse dots ----
// blocks [0,9216): convert; [9216,11520): transpose; [11520,11664): zero; [11664,11700): coarse
__global__ void prep(const float* __restrict__ g0, const float* __restrict__ g1,
                     const float* __restrict__ l0, const float* __restrict__ l1,
                     const float* __restrict__ k,
                     const float* __restrict__ c0, const float* __restrict__ c1,
                     const float* __restrict__ c2, const float* __restrict__ c3,
                     const float* __restrict__ c4, const float* __restrict__ c5,
                     unsigned short* __restrict__ outB,
                     unsigned short* __restrict__ kT,
                     unsigned* __restrict__ scratch,
                     float* __restrict__ out) {
    __shared__ float tile[32][33];
    const int bid = blockIdx.x;
    const int tid = threadIdx.x;
    if (bid < 9216) {
        // convert: layout [z][kt][n][32], physical chunk p = c ^ ((n>>1)&3)
        const int bx = bid % 576, z = bid / 576;
        const int b = z >> 2, t = z & 3;
        const float* src = t == 0 ? g0 : t == 1 ? g1 : t == 2 ? l0 : l1;
        const int kt = bx & 7;
        const int n0 = (bx >> 3) * 32;
        const int n = n0 + (tid >> 3);
        const int kk = (tid & 7) * 4;
        float4 v = *(const float4*)(src + (size_t)b * (HW * CD) + (size_t)n * CD + kt * 32 + kk);
        ushort4 o;
        o.x = f2bf(v.x); o.y = f2bf(v.y); o.z = f2bf(v.z); o.w = f2bf(v.w);
        const int p = (kk >> 3) ^ ((n >> 1) & 3);
        *(ushort4*)(outB + (size_t)z * (HW * CD) + (size_t)kt * (HW * 32)
                    + (size_t)n * 32 + p * 8 + (kk & 7)) = o;
    } else if (bid < 11520) {
        const int t3 = bid - 9216;              // orig grid (72,8,4)
        const int m0 = (t3 % 72) * 32;
        const int c0_ = ((t3 / 72) & 7) * 32;   // kt = c0_/32
        const int bz = t3 / 576;
        const int tx = tid & 31, ty = tid >> 5;
        const float* kb = k + (size_t)bz * CD * HW;
        #pragma unroll
        for (int s = 0; s < 32; s += 8)
            tile[ty + s][tx] = kb[(size_t)(c0_ + ty + s) * HW + m0 + tx];
        __syncthreads();
        unsigned short* kTb = kT + (size_t)bz * (HW * CD) + (size_t)(c0_ >> 5) * (HW * 32);
        #pragma unroll
        for (int s = 0; s < 32; s += 8) {
            const int m = m0 + ty + s;
            const int p = (tx >> 3) ^ ((m >> 1) & 3);
            kTb[(size_t)m * 32 + p * 8 + (tx & 7)] = f2bf(tile[tx][ty + s]);
        }
    } else if (bid < 11664) {
        const int i = (bid - 11520) * 256 + tid;   // 144*256 = 36864 = 16*HW
        scratch[i] = 0u;
    } else {
        const int g = (bid - 11664) * 256 + tid;   // 36*256 = 9216 = 4*HW
        const int b = g / HW, m = g - b * HW;
        float a0 = 0, a1 = 0, a2 = 0, a3 = 0, a4 = 0, a5 = 0;
        const float* kb = k + (size_t)b * CD * HW;
        for (int c = 0; c < CD; ++c) {
            const float kv = kb[(size_t)c * HW + m];
            a0 = fmaf(c0[b * CD + c], kv, a0);
            a1 = fmaf(c1[b * CD + c], kv, a1);
            a2 = fmaf(c2[b * CD + c], kv, a2);
            a3 = fmaf(c3[b * CD + c], kv, a3);
            a4 = fmaf(c4[b * CD + c], kv, a4);
            a5 = fmaf(c5[b * CD + c], kv, a5);
        }
        out[((size_t)b * 10 + 4) * HW + m] = a0;
        out[((size_t)b * 10 + 5) * HW + m] = a1;
        out[((size_t)b * 10 + 6) * HW + m] = a2;
        out[((size_t)b * 10 + 7) * HW + m] = a3;
        out[((size_t)b * 10 + 8) * HW + m] = a4;
        out[((size_t)b * 10 + 9) * HW + m] = a5;
    }
}

// ---- pass 2: dual-t MFMA GEMM, single-barrier K-loop + swizzled LDS ----
// grid 2592 linear. Balanced pair-swizzle: XCD pair {2c,2c+1} handles z in {2c,2c+1}.
__global__ __launch_bounds__(256, 2)
void fine_gemm(const unsigned short* __restrict__ memsB,  // [z][kt][2304][32] swz
               const unsigned short* __restrict__ kT,     // [b][kt][2304][32] swz
               const float* __restrict__ sds,
               unsigned* __restrict__ scratch) {
    __shared__ unsigned short A0l[2][128][32];   // 16KB
    __shared__ unsigned short A1l[2][128][32];   // 16KB
    __shared__ unsigned short Bl[2][128][32];    // 16KB

    const int h = blockIdx.x;
    const int x = h & 7, j = h >> 3;             // x = XCD slot, j in [0,324)
    const int c = x >> 1;                        // batch
    const int z = c * 2 + (j & 1);               // z in {2c, 2c+1}
    const int idx = (x & 1) * 162 + (j >> 1);    // tile index in [0,324)
    const int mi = idx % 18, ni = idx / 18;
    const int b = z >> 1, p = z & 1, t0 = p * 2;
    const int n0 = ni * 128, m0 = mi * 128;

    const int tid = threadIdx.x;
    const int lane = tid & 63;
    const int w = tid >> 6;
    const int wrow = w >> 1, wcol = w & 1;

    const unsigned short* A0g = memsB + (size_t)(b * 4 + t0) * (HW * CD);
    const unsigned short* A1g = memsB + (size_t)(b * 4 + t0 + 1) * (HW * CD);
    const unsigned short* Bg  = kT + (size_t)b * (HW * CD);

    const int srow = lane >> 2;          // staging: row within 16-row stripe
    const int scol = (lane & 3) * 8;     // staging: physical 16B chunk

    const int lr = lane & 15;
    const int pofs = ((lane >> 4) ^ ((lr >> 1) & 3)) * 8;   // swizzled read chunk

    f32x4 acc0[4][4] = {};
    f32x4 acc1[4][4] = {};

#define STAGE(buf, kt_)                                                                    \
    do {                                                                                   \
        const size_t ko = (size_t)(kt_) * (HW * 32);                                       \
        _Pragma("unroll")                                                                  \
        for (int s = 0; s < 2; ++s) {                                                      \
            const int r = w * 32 + s * 16;                                                 \
            const size_t goa = ko + (size_t)(n0 + r + srow) * 32 + scol;                   \
            const size_t gob = ko + (size_t)(m0 + r + srow) * 32 + scol;                   \
            __builtin_amdgcn_global_load_lds(                                              \
                (const __attribute__((address_space(1))) unsigned int*)(A0g + goa),        \
                (__attribute__((address_space(3))) unsigned int*)&A0l[buf][r][0], 16, 0, 0); \
            __builtin_amdgcn_global_load_lds(                                              \
                (const __attribute__((address_space(1))) unsigned int*)(A1g + goa),        \
                (__attribute__((address_space(3))) unsigned int*)&A1l[buf][r][0], 16, 0, 0); \
            __builtin_amdgcn_global_load_lds(                                              \
                (const __attribute__((address_space(1))) unsigned int*)(Bg + gob),         \
                (__attribute__((address_space(3))) unsigned int*)&Bl[buf][r][0], 16, 0, 0); \
        }                                                                                  \
    } while (0)

    STAGE(0, 0);
    STAGE(1, 1);
    asm volatile("s_waitcnt vmcnt(6)" ::: "memory");   // buf0 staged; buf1 in flight
    __builtin_amdgcn_s_barrier();

    #pragma unroll
    for (int kt = 0; kt < 8; ++kt) {
        const int cur = kt & 1;

        // R(kt): fragments from buf cur (ready per previous sync point)
        bf16x8 a0f[4], a1f[4], bfr[4];
        #pragma unroll
        for (int i = 0; i < 4; ++i) {
            a0f[i] = *(const bf16x8*)&A0l[cur][wrow * 64 + i * 16 + lr][pofs];
            a1f[i] = *(const bf16x8*)&A1l[cur][wrow * 64 + i * 16 + lr][pofs];
            bfr[i] = *(const bf16x8*)&Bl[cur][wcol * 64 + i * 16 + lr][pofs];
        }
        // my reads done (overwrite-safe) + stage(kt+1) landed (only it is outstanding)
        asm volatile("s_waitcnt lgkmcnt(0) vmcnt(0)" ::: "memory");
        __builtin_amdgcn_s_barrier();
        if (kt < 6) STAGE(cur, kt + 2);   // in flight across MFMA(kt) + R(kt+1)

        __builtin_amdgcn_s_setprio(1);
        #pragma unroll
        for (int i = 0; i < 4; ++i) {
            #pragma unroll
            for (int j2 = 0; j2 < 4; ++j2) {
                acc0[i][j2] = __builtin_amdgcn_mfma_f32_16x16x32_bf16(a0f[i], bfr[j2], acc0[i][j2], 0, 0, 0);
                acc1[i][j2] = __builtin_amdgcn_mfma_f32_16x16x32_bf16(a1f[i], bfr[j2], acc1[i][j2], 0, 0, 0);
            }
        }
        __builtin_amdgcn_s_setprio(0);
    }
#undef STAGE

    // epilogue: sds scale for the local pair (p == 1), one read serves both t's
    if (p == 1) {
        const float* sb = sds + (size_t)b * HW * HW;
        #pragma unroll
        for (int i = 0; i < 4; ++i) {
            #pragma unroll
            for (int j2 = 0; j2 < 4; ++j2) {
                #pragma unroll
                for (int r = 0; r < 4; ++r) {
                    const int n = n0 + wrow * 64 + i * 16 + (lane >> 4) * 4 + r;
                    const int m = m0 + wcol * 64 + j2 * 16 + (lane & 15);
                    const float sv = sb[(size_t)n * HW + m];
                    acc0[i][j2][r] *= sv;
                    acc1[i][j2][r] *= sv;
                }
            }
        }
    }

    // column max over the n (row) dimension per t, then device atomicMax
    #pragma unroll
    for (int j2 = 0; j2 < 4; ++j2) {
        float v0 = acc0[0][j2][0];
        float v1 = acc1[0][j2][0];
        #pragma unroll
        for (int i = 0; i < 4; ++i) {
            #pragma unroll
            for (int r = 0; r < 4; ++r) {
                v0 = fmaxf(v0, acc0[i][j2][r]);
                v1 = fmaxf(v1, acc1[i][j2][r]);
            }
        }
        v0 = fmaxf(v0, __shfl_xor(v0, 16));
        v0 = fmaxf(v0, __shfl_xor(v0, 32));
        v1 = fmaxf(v1, __shfl_xor(v1, 16));
        v1 = fmaxf(v1, __shfl_xor(v1, 32));
        if (lane < 16) {
            const int m = m0 + wcol * 64 + j2 * 16 + lane;
            atomicMax(&scratch[(size_t)(b * 4 + t0) * HW + m], fkey(v0));
            atomicMax(&scratch[(size_t)(b * 4 + t0 + 1) * HW + m], fkey(v1));
        }
    }
}

// ---- pass 3: decode fine maxes ----
__global__ void finalize(const unsigned* __restrict__ scratch, float* __restrict__ out) {
    const int i = blockIdx.x * 256 + threadIdx.x;   // 144*256 = 36864 = 16*HW
    const int z = i / HW, m = i - z * HW;
    const int b = z >> 2, t = z & 3;
    out[((size_t)b * 10 + t) * HW + m] = fdec(scratch[i]);
}

extern "C" void kernel_launch(void* const* d_in, const int* in_sizes, int n_in,
                              void* d_out, int out_size, void* d_ws, size_t ws_size,
                              hipStream_t stream) {
    const float* norm_key = (const float*)d_in[0];
    const float* gbg = (const float*)d_in[1];
    const float* gfg = (const float*)d_in[2];
    const float* lbg = (const float*)d_in[3];
    const float* lfg = (const float*)d_in[4];
    const float* obg = (const float*)d_in[5];
    const float* ofg = (const float*)d_in[6];
    const float* sbg = (const float*)d_in[7];
    const float* sfg = (const float*)d_in[8];
    const float* lgbg = (const float*)d_in[9];
    const float* lgfg = (const float*)d_in[10];
    const float* sds = (const float*)d_in[11];
    float* out = (float*)d_out;

    // ws layout: [scratch keys 16*2304 u32][memsB bf16 16*2304*256][kT bf16 4*2304*256]
    unsigned* scratch = (unsigned*)d_ws;
    const size_t scratch_bytes = (size_t)16 * HW * sizeof(unsigned);
    unsigned short* memsB = (unsigned short*)((char*)d_ws + scratch_bytes);
    const size_t mems_bytes = (size_t)16 * HW * CD * sizeof(unsigned short);
    unsigned short* kT = (unsigned short*)((char*)d_ws + scratch_bytes + mems_bytes);

    prep<<<11700, 256, 0, stream>>>(gbg, gfg, lbg, lfg, norm_key,
                                    obg, ofg, sbg, sfg, lgbg, lgfg,
                                    memsB, kT, scratch, out);
    fine_gemm<<<2592, 256, 0, stream>>>(memsB, kT, sds, scratch);
    finalize<<<144, 256, 0, stream>>>(scratch, out);
}